// Round 9
// baseline (549.657 us; speedup 1.0000x reference)
//
#include <hip/hip_runtime.h>
#include <math.h>

// Problem constants (fixed by reference setup_inputs)
#define NTOT 100
#define NQ   75
#define NP   25
#define CC   128
#define TT   8
#define VV   25
#define NCLS 5
#define NSUP 5
#define NQRY 15
#define ROW  (TT*VV*CC)   // 25600 floats per sample
#define TILE (VV*CC)      // 3200 floats per (n,t)
#define ROWS_Q 20000
#define ROWS_S 5000
#define RB_Q 625          // 20000/32 exact
#define RB_S 157          // ceil(5000/32)

typedef __attribute__((ext_vector_type(8))) short short8;
typedef __attribute__((ext_vector_type(16))) float f32x16;

typedef union { uint4 u4; short8 s8; } pk_t;

__device__ __forceinline__ ushort f2bf(float f) {
    uint u = __float_as_uint(f);
    u += 0x7FFFu + ((u >> 16) & 1u);   // RNE
    return (ushort)(u >> 16);
}
__device__ __forceinline__ float bf2f(uint u16v) {
    return __uint_as_float(u16v << 16);
}
__device__ __forceinline__ uint pkbf(float a, float b) {
    return (uint)f2bf(a) | ((uint)f2bf(b) << 16);
}

// ============ kernel 0: pack weights + compute gather order (ONCE) ============
__global__ __launch_bounds__(256) void k_pack(
    const float* __restrict__ Wq, const float* __restrict__ Wk,
    const float* __restrict__ Wv, const float* __restrict__ Wo,
    const int* __restrict__ target,
    ushort* __restrict__ WfG, int* __restrict__ ordG) {
    int which = blockIdx.x;
    if (which == 4) {
        __shared__ int tg[NTOT];
        int tid = threadIdx.x;
        if (tid < NTOT) tg[tid] = target[tid];
        __syncthreads();
        if (tid < NTOT) {
            int ti = tg[tid], rank = 0;
            for (int j = 0; j < NTOT; ++j) {
                int tj = tg[j];
                rank += (tj < ti) || (tj == ti && j < tid);
            }
            ordG[rank] = tid;
        }
        return;
    }
    const float* W = (which == 0) ? Wq : (which == 1) ? Wk : (which == 2) ? Wv : Wo;
    ushort* dstbase = WfG + (size_t)which * 16384;
    for (int o = threadIdx.x; o < 2048; o += 256) {
        int k8 = o >> 7, c = o & 127;
        uint4 pk;
        pk.x = pkbf(W[(k8*8+0)*128 + c], W[(k8*8+1)*128 + c]);
        pk.y = pkbf(W[(k8*8+2)*128 + c], W[(k8*8+3)*128 + c]);
        pk.z = pkbf(W[(k8*8+4)*128 + c], W[(k8*8+5)*128 + c]);
        pk.w = pkbf(W[(k8*8+6)*128 + c], W[(k8*8+7)*128 + c]);
        int dst = (((c >> 5) * 8 + (k8 >> 1)) * 64 + ((c & 31) + 32 * (k8 & 1))) * 8;
        *(uint4*)(dstbase + dst) = pk;
    }
}

// ============ kernel 1: fused gather + projections ============
// 32 tv-rows per block (r7: bigger blocks regress — per-block latency rules).
// blocks 0..156: K/V path (heavy, first); blocks 157..781: Q path (+catC).
__global__ __launch_bounds__(256) void k_proj(
    const float* __restrict__ input, const int* __restrict__ ordG,
    const ushort* __restrict__ WfG,
    const float* __restrict__ bq, const float* __restrict__ bk,
    const float* __restrict__ bv,
    ushort* __restrict__ catC, ushort* __restrict__ Qf,
    ushort* __restrict__ Kf, ushort* __restrict__ Vf,
    int* __restrict__ counter) {
    __shared__ ushort stage[32 * 132];   // A rows bf16, stride-132
    __shared__ ushort VtF[4096];         // Vt A-frags (KV stage-2)

    int bid = blockIdx.x, tid = threadIdx.x;
    int w = tid >> 6, lane = tid & 63, half = lane >> 5, l31 = lane & 31;

    if (bid == 0 && tid == 0) *counter = 0;   // ticket for k_dist_loss

    bool isQ = bid >= RB_S;
    int rowblk = isQ ? bid - RB_S : bid;
    int rlimit = isQ ? ROWS_Q : ROWS_S;
    int g0 = rowblk * 32;
    int gend = min(g0 + 32, rlimit);

    // ---- stage A rows [g0, gend) into LDS (float4 loads, bf16 convert) ----
    for (int nn = g0 / 200; nn <= (gend - 1) / 200; ++nn) {
        int lo = max(g0 - nn * 200, 0);
        int hi = min(gend - 1 - nn * 200, 199);
        int len = hi - lo + 1;
        int nidx = isQ ? nn : (NQ + nn);
        int src;
        if (nidx < NQ) { int m = nidx / NQRY, qq = nidx - m * NQRY; src = ordG[m * 20 + NSUP + qq]; }
        else           { int i2 = nidx - NQ; int m = i2 / NSUP, s = i2 - m * NSUP; src = ordG[m * 20 + s]; }
        const float* inb = input + (size_t)src * ROW + lo;
        int rbase = nn * 200 + lo - g0;
        int nv4 = len >> 2;                 // len ≡ 0 mod 4 always
        int total4 = nv4 << 7;              // nv4 * 128 cols
        int qstep = 256 / nv4, rstep = 256 - qstep * nv4;
        int c = tid / nv4, v = tid - c * nv4;
        for (int idx = tid; idx < total4; idx += 256) {
            int k = v << 2;
            float4 f = *(const float4*)(inb + c * 200 + k);
            int ro = (rbase + k) * 132 + c;
            stage[ro]       = f2bf(f.x);
            stage[ro + 132] = f2bf(f.y);
            stage[ro + 264] = f2bf(f.z);
            stage[ro + 396] = f2bf(f.w);
            c += qstep; v += rstep;
            if (v >= nv4) { v -= nv4; ++c; }
        }
    }
    __syncthreads();   // stage ready

    // ---- A-frags from LDS stage (shared by all waves) ----
    short8 af[8];
    #pragma unroll
    for (int ks = 0; ks < 8; ++ks)
        af[ks] = *(const short8*)&stage[l31 * 132 + ks * 16 + half * 8];

    #define CHAIN(A, OUT, BASE) do {                                             \
        const ushort* bp_ = (BASE) + w * 4096 + lane * 8;                        \
        _Pragma("unroll")                                                        \
        for (int ks = 0; ks < 8; ++ks) {                                         \
            short8 bf_ = *(const short8*)(bp_ + ks * 512);                       \
            OUT = __builtin_amdgcn_mfma_f32_32x32x16_bf16(A[ks], bf_, OUT, 0, 0, 0); \
        }                                                                        \
    } while (0)

    if (isQ) {
        f32x16 Cm;
        #pragma unroll
        for (int r = 0; r < 16; ++r) Cm[r] = 0.f;
        CHAIN(af, Cm, WfG);
        float bcol = bq[w * 32 + l31];
        int c = w * 32 + l31;
        #pragma unroll
        for (int r = 0; r < 16; ++r) {
            int row = g0 + (r & 3) + 8 * (r >> 2) + 4 * half;   // all Q rows valid
            int st = row / 25, vv = row - st * 25;
            size_t dst = (((size_t)st * 8 + (c >> 4)) * 64 + (vv + 32 * ((c >> 3) & 1))) * 8 + (c & 7);
            Qf[dst] = f2bf(Cm[r] + bcol);
        }
        // catC bf16 [row][c] cooperatively from stage
        uint* cc = (uint*)catC + (size_t)g0 * 64;
        for (int idx = tid; idx < 2048; idx += 256) {
            int row = idx >> 6, c2 = (idx & 63) * 2;
            cc[idx] = (uint)stage[row * 132 + c2] | ((uint)stage[row * 132 + c2 + 1] << 16);
        }
    } else {
        // ---- K ----
        {
            f32x16 Cm;
            #pragma unroll
            for (int r = 0; r < 16; ++r) Cm[r] = 0.f;
            CHAIN(af, Cm, WfG + 16384);
            float bcol = bk[w * 32 + l31];
            int c = w * 32 + l31;
            #pragma unroll
            for (int r = 0; r < 16; ++r) {
                int row = g0 + (r & 3) + 8 * (r >> 2) + 4 * half;
                if (row < ROWS_S) {
                    int st = row / 25, vv = row - st * 25;
                    size_t dst = (((size_t)st * 8 + (c >> 4)) * 64 + (vv + 32 * ((c >> 3) & 1))) * 8 + (c & 7);
                    Kf[dst] = f2bf(Cm[r] + bcol);
                }
            }
        }
        // ---- Vt = supp@Wv + bv -> A-frags in VtF ----
        {
            f32x16 Cm;
            #pragma unroll
            for (int r = 0; r < 16; ++r) Cm[r] = 0.f;
            CHAIN(af, Cm, WfG + 32768);
            float bcol = bv[w * 32 + l31];
            int c = w * 32 + l31;
            int ks2 = c >> 4, kh = (c >> 3) & 1, j2 = c & 7;
            #pragma unroll
            for (int r = 0; r < 16; ++r) {
                int rowLocal = (r & 3) + 8 * (r >> 2) + 4 * half;
                VtF[ks2 * 512 + (rowLocal + 32 * kh) * 8 + j2] = f2bf(Cm[r] + bcol);
            }
        }
        __syncthreads();   // VtF written (cross-wave read next)
        // ---- V = Vt @ Wo -> Vf frags ----
        short8 a2[8];
        #pragma unroll
        for (int ks = 0; ks < 8; ++ks)
            a2[ks] = *(const short8*)&VtF[ks * 512 + lane * 8];
        {
            f32x16 Cm;
            #pragma unroll
            for (int r = 0; r < 16; ++r) Cm[r] = 0.f;
            CHAIN(a2, Cm, WfG + 49152);
            int c = w * 32 + l31;
            #pragma unroll
            for (int r = 0; r < 16; ++r) {
                int row = g0 + (r & 3) + 8 * (r >> 2) + 4 * half;
                if (row < ROWS_S) {
                    int tile = row / 25, vv = row - tile * 25;
                    size_t dst = ((((size_t)tile * 4 + (c >> 5)) * 2 + (vv >> 4)) * 64
                                  + ((c & 31) + 32 * ((vv & 15) >> 3))) * 8 + (vv & 7);
                    Vf[dst] = f2bf(Cm[r]);
                }
            }
        }
    }
    #undef CHAIN
}

// ============ kernel 2: MFMA fused attention + residual + LN ============
// Round-9 change: kill the register spill that dominates the m-loop.
// Old: attsum[64] regs/thread (4 waves x full copy) + kf prefetch -> ~200 live
// regs vs 128 cap -> ~60 regs spilled/reloaded EVERY iteration (WRITE_SIZE
// showed 14 MB spill; m-loop was L2-bound on scratch). New: accumulate into an
// LDS accumulator via ds_add_f32 atomics (output/block is only 25x128 floats),
// load kf per-iteration (Kf is L2-hot). Peak live ~115 regs -> no spill. Also
// deletes the entire 4-barrier cross-wave reduce tail.
// attacc stride 129: bank = q*129%32 = q -> conflict-free (half-pairs 2-way = free).
__global__ __launch_bounds__(256, 2) void k_attn(
    const ushort* __restrict__ Qf, const ushort* __restrict__ Kf,
    const ushort* __restrict__ Vf, const ushort* __restrict__ catC,
    const float* __restrict__ bo, float* __restrict__ att) {
    // LDS: catb f32[25*129] @0 (12912B) | qls u16[4096] @12912 (8192B)
    //      attacc f32[32*129] @21104 (16512B) | cscacc f32[32] @37616 (128B)
    __shared__ __align__(16) char smem[37744];
    float*  catb   = (float*)smem;
    ushort* qls    = (ushort*)(smem + 12912);
    float*  attacc = (float*)(smem + 21104);
    float*  cscacc = attacc + 32 * 129;

    int pair = blockIdx.x;                    // n*8 + t
    int t = pair & 7;
    int tid = threadIdx.x;
    int wv = tid >> 6, lane = tid & 63;
    int q = lane & 31, half = lane >> 5;

    {
        const uint* cc = (const uint*)catC + (size_t)pair * 1600;
        for (int i2 = tid; i2 < 1600; i2 += 256) {
            uint u = cc[i2];
            int r = i2 >> 6, c2 = (i2 & 63) * 2;
            catb[r * 129 + c2]     = bf2f(u & 0xffffu) + bo[c2];
            catb[r * 129 + c2 + 1] = bf2f(u >> 16) + bo[c2 + 1];
        }
    }
    {
        const uint* qp = (const uint*)(Qf + (size_t)pair * 4096);
        uint* ql = (uint*)qls;
        for (int i2 = tid; i2 < 2048; i2 += 256) ql[i2] = qp[i2];
    }
    for (int i2 = tid; i2 < 32 * 129 + 32; i2 += 256) attacc[i2] = 0.f;  // attacc+cscacc
    __syncthreads();

    int qc = q < 25 ? q : 24;
    bool act = q < 25;

    const float CEXP = (float)(1.4426950408889634 * 0.08838834764831845);

    const ushort* kbase = Kf + (size_t)t * 4096 + lane * 8;

    int cnt = (wv == 0) ? 7 : 6;
    for (int mi = 0; mi < cnt; ++mi) {
        int m = wv + 4 * mi;

        // K frags for this m (no cross-iteration prefetch: 32 regs at peak
        // pressure cost more in spill than the exposed L2 latency here)
        short8 kf[8];
        #pragma unroll
        for (int ks = 0; ks < 8; ++ks)
            kf[ks] = *(const short8*)(kbase + (size_t)m * 32768 + ks * 512);

        f32x16 S;
        #pragma unroll
        for (int r = 0; r < 16; ++r) S[r] = 0.f;
        #pragma unroll
        for (int ks = 0; ks < 8; ++ks) {
            short8 qv = *(const short8*)(qls + ks * 512 + lane * 8);
            S = __builtin_amdgcn_mfma_f32_32x32x16_bf16(kf[ks], qv, S, 0, 0, 0);
        }

        float p[16], mx = -3e38f;
        #pragma unroll
        for (int r = 0; r < 16; ++r) {
            int key = (r & 3) + 8 * (r >> 2) + 4 * half;
            float v = (key < 25) ? S[r] : -3e38f;
            p[r] = v; mx = fmaxf(mx, v);
        }
        mx = fmaxf(mx, __shfl_xor(mx, 32));
        float sum = 0.f;
        #pragma unroll
        for (int r = 0; r < 16; ++r) { p[r] = exp2f((p[r] - mx) * CEXP); sum += p[r]; }
        sum += __shfl_xor(sum, 32);
        float inv = 1.f / sum;

        const ushort* vp = Vf + ((size_t)(m * 8 + t)) * 4096 + lane * 8;
        short8 vf0 = *(const short8*)(vp);
        short8 vf1 = *(const short8*)(vp + 512);
        short8 vf2 = *(const short8*)(vp + 1024);
        short8 vf3 = *(const short8*)(vp + 1536);
        short8 vf4 = *(const short8*)(vp + 2048);
        short8 vf5 = *(const short8*)(vp + 2560);
        short8 vf6 = *(const short8*)(vp + 3072);
        short8 vf7 = *(const short8*)(vp + 3584);

        uint o01   = pkbf(p[0] * inv,  p[1] * inv);
        uint o23   = pkbf(p[2] * inv,  p[3] * inv);
        uint o45   = pkbf(p[4] * inv,  p[5] * inv);
        uint o67   = pkbf(p[6] * inv,  p[7] * inv);
        uint o89   = pkbf(p[8] * inv,  p[9] * inv);
        uint o1011 = pkbf(p[10] * inv, p[11] * inv);
        uint o1213 = pkbf(p[12] * inv, p[13] * inv);
        uint o1415 = pkbf(p[14] * inv, p[15] * inv);
        bool h0 = (half == 0);
        uint rA = __shfl_xor(h0 ? o45 : o01, 32);
        uint rB = __shfl_xor(h0 ? o67 : o23, 32);
        uint rC = __shfl_xor(h0 ? o1213 : o89, 32);
        uint rD = __shfl_xor(h0 ? o1415 : o1011, 32);
        pk_t P0, P1;
        P0.u4 = h0 ? make_uint4(o01, o23, rA, rB) : make_uint4(rA, rB, o45, o67);
        P1.u4 = h0 ? make_uint4(o89, o1011, rC, rD) : make_uint4(rC, rD, o1213, o1415);
        short8 pb0 = P0.s8, pb1 = P1.s8;

        f32x16 ctx[4];
        #pragma unroll
        for (int mt = 0; mt < 4; ++mt) {
            #pragma unroll
            for (int r = 0; r < 16; ++r) ctx[mt][r] = 0.f;
        }
        ctx[0] = __builtin_amdgcn_mfma_f32_32x32x16_bf16(vf0, pb0, ctx[0], 0, 0, 0);
        ctx[0] = __builtin_amdgcn_mfma_f32_32x32x16_bf16(vf1, pb1, ctx[0], 0, 0, 0);
        ctx[1] = __builtin_amdgcn_mfma_f32_32x32x16_bf16(vf2, pb0, ctx[1], 0, 0, 0);
        ctx[1] = __builtin_amdgcn_mfma_f32_32x32x16_bf16(vf3, pb1, ctx[1], 0, 0, 0);
        ctx[2] = __builtin_amdgcn_mfma_f32_32x32x16_bf16(vf4, pb0, ctx[2], 0, 0, 0);
        ctx[2] = __builtin_amdgcn_mfma_f32_32x32x16_bf16(vf5, pb1, ctx[2], 0, 0, 0);
        ctx[3] = __builtin_amdgcn_mfma_f32_32x32x16_bf16(vf6, pb0, ctx[3], 0, 0, 0);
        ctx[3] = __builtin_amdgcn_mfma_f32_32x32x16_bf16(vf7, pb1, ctx[3], 0, 0, 0);

        float s1 = 0.f, s2 = 0.f;
        #pragma unroll
        for (int mt = 0; mt < 4; ++mt) {
            float t1 = 0.f, t2 = 0.f;
            #pragma unroll
            for (int r = 0; r < 16; ++r) {
                int c = mt * 32 + (r & 3) + 8 * (r >> 2) + 4 * half;
                float xv = ctx[mt][r] + catb[qc * 129 + c];
                ctx[mt][r] = xv;
                t1 += xv; t2 = fmaf(xv, xv, t2);
            }
            s1 += t1; s2 += t2;
        }
        s1 += __shfl_xor(s1, 32); s2 += __shfl_xor(s2, 32);
        float mu = s1 * (1.f / 128.f);
        float var = s2 * (1.f / 128.f) - mu * mu;
        var = fmaxf(var, 0.f);
        float rs = rsqrtf(var + 1e-12f);

        if (act) {
            float* arow = attacc + q * 129;
            #pragma unroll
            for (int mt = 0; mt < 4; ++mt) {
                #pragma unroll
                for (int r = 0; r < 16; ++r) {
                    int c = mt * 32 + (r & 3) + 8 * (r >> 2) + 4 * half;
                    atomicAdd(&arow[c], ctx[mt][r] * rs);
                }
            }
            if (h0) atomicAdd(&cscacc[q], -mu * rs);
        }
    }

    __syncthreads();
    // epilogue: att[pair][q][c] = attacc[q][c] + cscacc[q]  (800 float4 stores)
    {
        float* ap = att + (size_t)pair * TILE;
        for (int idx = tid; idx < 800; idx += 256) {
            int qq = idx >> 5, c4 = (idx & 31) * 4;
            float cs = cscacc[qq];
            const float* ar = attacc + qq * 129 + c4;
            float4 o;
            o.x = ar[0] + cs; o.y = ar[1] + cs; o.z = ar[2] + cs; o.w = ar[3] + cs;
            *(float4*)&ap[qq * 128 + c4] = o;
        }
    }
}

// ============ kernel 2.5: materialize protos (mean of 5 support rows) ============
__global__ __launch_bounds__(256) void k_proto(
    const float* __restrict__ att, float* __restrict__ proto) {
    int b = blockIdx.x;             // 40 blocks: j = b>>3, chunk = b&7
    int j = b >> 3, chunk = b & 7;
    const float4* s0 = (const float4*)(att + (size_t)(NQ + j * 5 + 0) * ROW);
    const float4* s1 = (const float4*)(att + (size_t)(NQ + j * 5 + 1) * ROW);
    const float4* s2 = (const float4*)(att + (size_t)(NQ + j * 5 + 2) * ROW);
    const float4* s3 = (const float4*)(att + (size_t)(NQ + j * 5 + 3) * ROW);
    const float4* s4 = (const float4*)(att + (size_t)(NQ + j * 5 + 4) * ROW);
    float4* pr = (float4*)(proto + (size_t)j * ROW);
    int e0 = chunk * 800, e1 = e0 + 800;
    for (int e4 = e0 + threadIdx.x; e4 < e1; e4 += 256) {
        float4 q0 = s0[e4], q1 = s1[e4], q2 = s2[e4], q3 = s3[e4], q4 = s4[e4];
        float4 o;
        o.x = 0.2f * (q0.x + q1.x + q2.x + q3.x + q4.x);
        o.y = 0.2f * (q0.y + q1.y + q2.y + q3.y + q4.y);
        o.z = 0.2f * (q0.z + q1.z + q2.z + q3.z + q4.z);
        o.w = 0.2f * (q0.w + q1.w + q2.w + q3.w + q4.w);
        pr[e4] = o;
    }
}

// ============ kernel 3: fused distances + log-softmax loss/acc ============
__global__ __launch_bounds__(256) void k_dist_loss(
    const float* __restrict__ att, const float* __restrict__ proto,
    const float* __restrict__ ln_g,
    float* __restrict__ dist, int* __restrict__ counter,
    float* __restrict__ out) {
    int i = blockIdx.x;   // query index 0..74
    const float4* a  = (const float4*)(att + (size_t)i * ROW);
    const float4* p0 = (const float4*)(proto + (size_t)0 * ROW);
    const float4* p1 = (const float4*)(proto + (size_t)1 * ROW);
    const float4* p2 = (const float4*)(proto + (size_t)2 * ROW);
    const float4* p3 = (const float4*)(proto + (size_t)3 * ROW);
    const float4* p4 = (const float4*)(proto + (size_t)4 * ROW);
    float d0 = 0.f, d1 = 0.f, d2 = 0.f, d3 = 0.f, d4 = 0.f;
    for (int e4 = threadIdx.x; e4 < 6400; e4 += 256) {
        float4 av = a[e4];
        float4 g4 = *(const float4*)(ln_g + (e4 & 31) * 4);
        float gx = g4.x * g4.x, gy = g4.y * g4.y, gz = g4.z * g4.z, gw = g4.w * g4.w;
        #define ACC(PD, DD) do {                                              \
            float4 pv = PD[e4];                                               \
            float dx = av.x - pv.x, dy = av.y - pv.y;                         \
            float dz = av.z - pv.z, dw = av.w - pv.w;                         \
            DD = fmaf(gx, dx * dx, DD);                                       \
            DD = fmaf(gy, dy * dy, DD);                                       \
            DD = fmaf(gz, dz * dz, DD);                                       \
            DD = fmaf(gw, dw * dw, DD);                                       \
        } while (0)
        ACC(p0, d0); ACC(p1, d1); ACC(p2, d2); ACC(p3, d3); ACC(p4, d4);
        #undef ACC
    }
    #pragma unroll
    for (int msk = 32; msk >= 1; msk >>= 1) {
        d0 += __shfl_xor(d0, msk);
        d1 += __shfl_xor(d1, msk);
        d2 += __shfl_xor(d2, msk);
        d3 += __shfl_xor(d3, msk);
        d4 += __shfl_xor(d4, msk);
    }
    __shared__ float part[4][5];
    __shared__ int lastFlag;
    int lane = threadIdx.x & 63, wv = threadIdx.x >> 6;
    if (lane == 0) {
        part[wv][0] = d0; part[wv][1] = d1; part[wv][2] = d2;
        part[wv][3] = d3; part[wv][4] = d4;
    }
    __syncthreads();
    if (threadIdx.x == 0) {
        #pragma unroll
        for (int j = 0; j < 5; ++j) {
            float total = (part[0][j] + part[1][j] + part[2][j] + part[3][j]) * (1.f / 625.f);
            __hip_atomic_store(&dist[i * 5 + j], total, __ATOMIC_RELEASE, __HIP_MEMORY_SCOPE_AGENT);
        }
        int tk = __hip_atomic_fetch_add(counter, 1, __ATOMIC_ACQ_REL, __HIP_MEMORY_SCOPE_AGENT);
        lastFlag = (tk == 74);
    }
    __syncthreads();
    if (!lastFlag) return;

    int iq = threadIdx.x;
    float li = 0.f, ok = 0.f;
    if (iq < NQ) {
        float dd[5];
        #pragma unroll
        for (int jj = 0; jj < 5; ++jj)
            dd[jj] = __hip_atomic_load(&dist[iq * 5 + jj], __ATOMIC_ACQUIRE, __HIP_MEMORY_SCOPE_AGENT);
        int cls = iq / NQRY;
        float mind = dd[0];
        int best = 0;
        #pragma unroll
        for (int jj = 1; jj < 5; ++jj) {
            if (dd[jj] < mind) mind = dd[jj];
            if (dd[jj] < dd[best]) best = jj;
        }
        float sume = 0.f;
        #pragma unroll
        for (int jj = 0; jj < 5; ++jj) sume += expf(mind - dd[jj]);
        float lse = logf(sume) - mind;
        li = dd[cls] + lse;
        ok = (best == cls) ? 1.f : 0.f;
    }
    #pragma unroll
    for (int msk = 32; msk >= 1; msk >>= 1) {
        li += __shfl_xor(li, msk);
        ok += __shfl_xor(ok, msk);
    }
    if (lane == 0) { part[wv][0] = li; part[wv][1] = ok; }
    __syncthreads();
    if (threadIdx.x == 0) {
        out[0] = (part[0][0] + part[1][0] + part[2][0] + part[3][0]) / 75.f;
        out[1] = (part[0][1] + part[1][1] + part[2][1] + part[3][1]) / 75.f;
    }
}

extern "C" void kernel_launch(void* const* d_in, const int* in_sizes, int n_in,
                              void* d_out, int out_size, void* d_ws, size_t ws_size,
                              hipStream_t stream) {
    const float* input = (const float*)d_in[0];
    const float* Wq   = (const float*)d_in[1];
    const float* bq   = (const float*)d_in[2];
    const float* Wk   = (const float*)d_in[3];
    const float* bk   = (const float*)d_in[4];
    const float* Wv   = (const float*)d_in[5];
    const float* bv   = (const float*)d_in[6];
    const float* Wo   = (const float*)d_in[7];
    const float* bo   = (const float*)d_in[8];
    const float* ln_g = (const float*)d_in[9];
    const float* ln_b = (const float*)d_in[10];  // cancels in the distance
    const int* target = (const int*)d_in[11];
    float* out = (float*)d_out;
    (void)ln_b;

    float* ws = (float*)d_ws;
    ushort* catC = (ushort*)ws;                              // 2,560,000 u16
    ushort* Qf   = catC + 2560000;                           // 3,276,800
    ushort* Kf   = Qf + 3276800;                             //   819,200
    ushort* Vf   = Kf + 819200;                              //   819,200
    float*  att  = (float*)(Vf + 819200);                    // 100*25600 fp32
    float*  distb = att + 2560000;                           // 375 (+pad)
    int*    counter = (int*)(distb + 512);
    ushort* WfG  = (ushort*)(counter + 16);                  // 4 x 16384 u16 = 128 KB
    int*    ordG = (int*)(WfG + 65536);                      // 100 ints
    // proto aliases catC: catC's last reader is k_attn; k_proto runs after.
    float*  proto = (float*)catC;                            // 5*25600 fp32 = 512 KB
    // total ~25.3 MB

    k_pack<<<5, 256, 0, stream>>>(Wq, Wk, Wv, Wo, target, WfG, ordG);
    k_proj<<<RB_Q + RB_S, 256, 0, stream>>>(input, ordG, WfG, bq, bk, bv,
                                            catC, Qf, Kf, Vf, counter);
    k_attn<<<800, 256, 0, stream>>>(Qf, Kf, Vf, catC, bo, att);
    k_proto<<<40, 256, 0, stream>>>(att, proto);
    k_dist_loss<<<75, 256, 0, stream>>>(att, proto, ln_g, distb, counter, out);
}

// Round 10
// 169.126 us; speedup vs baseline: 3.2500x; 3.2500x over previous
//
#include <hip/hip_runtime.h>
#include <math.h>

// Problem constants (fixed by reference setup_inputs)
#define NTOT 100
#define NQ   75
#define NP   25
#define CC   128
#define TT   8
#define VV   25
#define NCLS 5
#define NSUP 5
#define NQRY 15
#define ROW  (TT*VV*CC)   // 25600 floats per sample
#define TILE (VV*CC)      // 3200 floats per (n,t)
#define ROWS_Q 20000
#define ROWS_S 5000
#define RB_Q 625          // 20000/32 exact
#define RB_S 157          // ceil(5000/32)

typedef __attribute__((ext_vector_type(8))) short short8;
typedef __attribute__((ext_vector_type(16))) float f32x16;

typedef union { uint4 u4; short8 s8; } pk_t;

__device__ __forceinline__ ushort f2bf(float f) {
    uint u = __float_as_uint(f);
    u += 0x7FFFu + ((u >> 16) & 1u);   // RNE
    return (ushort)(u >> 16);
}
__device__ __forceinline__ float bf2f(uint u16v) {
    return __uint_as_float(u16v << 16);
}
__device__ __forceinline__ uint pkbf(float a, float b) {
    return (uint)f2bf(a) | ((uint)f2bf(b) << 16);
}

// ============ kernel 0: pack weights + compute gather order (ONCE) ============
__global__ __launch_bounds__(256) void k_pack(
    const float* __restrict__ Wq, const float* __restrict__ Wk,
    const float* __restrict__ Wv, const float* __restrict__ Wo,
    const int* __restrict__ target,
    ushort* __restrict__ WfG, int* __restrict__ ordG) {
    int which = blockIdx.x;
    if (which == 4) {
        __shared__ int tg[NTOT];
        int tid = threadIdx.x;
        if (tid < NTOT) tg[tid] = target[tid];
        __syncthreads();
        if (tid < NTOT) {
            int ti = tg[tid], rank = 0;
            for (int j = 0; j < NTOT; ++j) {
                int tj = tg[j];
                rank += (tj < ti) || (tj == ti && j < tid);
            }
            ordG[rank] = tid;
        }
        return;
    }
    const float* W = (which == 0) ? Wq : (which == 1) ? Wk : (which == 2) ? Wv : Wo;
    ushort* dstbase = WfG + (size_t)which * 16384;
    for (int o = threadIdx.x; o < 2048; o += 256) {
        int k8 = o >> 7, c = o & 127;
        uint4 pk;
        pk.x = pkbf(W[(k8*8+0)*128 + c], W[(k8*8+1)*128 + c]);
        pk.y = pkbf(W[(k8*8+2)*128 + c], W[(k8*8+3)*128 + c]);
        pk.z = pkbf(W[(k8*8+4)*128 + c], W[(k8*8+5)*128 + c]);
        pk.w = pkbf(W[(k8*8+6)*128 + c], W[(k8*8+7)*128 + c]);
        int dst = (((c >> 5) * 8 + (k8 >> 1)) * 64 + ((c & 31) + 32 * (k8 & 1))) * 8;
        *(uint4*)(dstbase + dst) = pk;
    }
}

// ============ kernel 1: fused gather + projections ============
// 32 tv-rows per block (r7: 128-row blocks regress — per-block latency rules).
// blocks 0..156: K/V path (heavy, first); blocks 157..781: Q path (+catC).
__global__ __launch_bounds__(256) void k_proj(
    const float* __restrict__ input, const int* __restrict__ ordG,
    const ushort* __restrict__ WfG,
    const float* __restrict__ bq, const float* __restrict__ bk,
    const float* __restrict__ bv,
    ushort* __restrict__ catC, ushort* __restrict__ Qf,
    ushort* __restrict__ Kf, ushort* __restrict__ Vf,
    int* __restrict__ counter) {
    __shared__ ushort stage[32 * 132];   // A rows bf16, stride-132
    __shared__ ushort VtF[4096];         // Vt A-frags (KV stage-2)

    int bid = blockIdx.x, tid = threadIdx.x;
    int w = tid >> 6, lane = tid & 63, half = lane >> 5, l31 = lane & 31;

    if (bid == 0 && tid == 0) *counter = 0;   // ticket for k_dist_loss

    bool isQ = bid >= RB_S;
    int rowblk = isQ ? bid - RB_S : bid;
    int rlimit = isQ ? ROWS_Q : ROWS_S;
    int g0 = rowblk * 32;
    int gend = min(g0 + 32, rlimit);

    // ---- stage A rows [g0, gend) into LDS (float4 loads, bf16 convert) ----
    for (int nn = g0 / 200; nn <= (gend - 1) / 200; ++nn) {
        int lo = max(g0 - nn * 200, 0);
        int hi = min(gend - 1 - nn * 200, 199);
        int len = hi - lo + 1;
        int nidx = isQ ? nn : (NQ + nn);
        int src;
        if (nidx < NQ) { int m = nidx / NQRY, qq = nidx - m * NQRY; src = ordG[m * 20 + NSUP + qq]; }
        else           { int i2 = nidx - NQ; int m = i2 / NSUP, s = i2 - m * NSUP; src = ordG[m * 20 + s]; }
        const float* inb = input + (size_t)src * ROW + lo;
        int rbase = nn * 200 + lo - g0;
        int nv4 = len >> 2;                 // len ≡ 0 mod 4 always
        int total4 = nv4 << 7;              // nv4 * 128 cols
        int qstep = 256 / nv4, rstep = 256 - qstep * nv4;
        int c = tid / nv4, v = tid - c * nv4;
        for (int idx = tid; idx < total4; idx += 256) {
            int k = v << 2;
            float4 f = *(const float4*)(inb + c * 200 + k);
            int ro = (rbase + k) * 132 + c;
            stage[ro]       = f2bf(f.x);
            stage[ro + 132] = f2bf(f.y);
            stage[ro + 264] = f2bf(f.z);
            stage[ro + 396] = f2bf(f.w);
            c += qstep; v += rstep;
            if (v >= nv4) { v -= nv4; ++c; }
        }
    }
    __syncthreads();   // stage ready

    // ---- A-frags from LDS stage (shared by all waves) ----
    short8 af[8];
    #pragma unroll
    for (int ks = 0; ks < 8; ++ks)
        af[ks] = *(const short8*)&stage[l31 * 132 + ks * 16 + half * 8];

    #define CHAIN(A, OUT, BASE) do {                                             \
        const ushort* bp_ = (BASE) + w * 4096 + lane * 8;                        \
        _Pragma("unroll")                                                        \
        for (int ks = 0; ks < 8; ++ks) {                                         \
            short8 bf_ = *(const short8*)(bp_ + ks * 512);                       \
            OUT = __builtin_amdgcn_mfma_f32_32x32x16_bf16(A[ks], bf_, OUT, 0, 0, 0); \
        }                                                                        \
    } while (0)

    if (isQ) {
        f32x16 Cm;
        #pragma unroll
        for (int r = 0; r < 16; ++r) Cm[r] = 0.f;
        CHAIN(af, Cm, WfG);
        float bcol = bq[w * 32 + l31];
        int c = w * 32 + l31;
        #pragma unroll
        for (int r = 0; r < 16; ++r) {
            int row = g0 + (r & 3) + 8 * (r >> 2) + 4 * half;   // all Q rows valid
            int st = row / 25, vv = row - st * 25;
            size_t dst = (((size_t)st * 8 + (c >> 4)) * 64 + (vv + 32 * ((c >> 3) & 1))) * 8 + (c & 7);
            Qf[dst] = f2bf(Cm[r] + bcol);
        }
        // catC bf16 [row][c] cooperatively from stage
        uint* cc = (uint*)catC + (size_t)g0 * 64;
        for (int idx = tid; idx < 2048; idx += 256) {
            int row = idx >> 6, c2 = (idx & 63) * 2;
            cc[idx] = (uint)stage[row * 132 + c2] | ((uint)stage[row * 132 + c2 + 1] << 16);
        }
    } else {
        // ---- K ----
        {
            f32x16 Cm;
            #pragma unroll
            for (int r = 0; r < 16; ++r) Cm[r] = 0.f;
            CHAIN(af, Cm, WfG + 16384);
            float bcol = bk[w * 32 + l31];
            int c = w * 32 + l31;
            #pragma unroll
            for (int r = 0; r < 16; ++r) {
                int row = g0 + (r & 3) + 8 * (r >> 2) + 4 * half;
                if (row < ROWS_S) {
                    int st = row / 25, vv = row - st * 25;
                    size_t dst = (((size_t)st * 8 + (c >> 4)) * 64 + (vv + 32 * ((c >> 3) & 1))) * 8 + (c & 7);
                    Kf[dst] = f2bf(Cm[r] + bcol);
                }
            }
        }
        // ---- Vt = supp@Wv + bv -> A-frags in VtF ----
        {
            f32x16 Cm;
            #pragma unroll
            for (int r = 0; r < 16; ++r) Cm[r] = 0.f;
            CHAIN(af, Cm, WfG + 32768);
            float bcol = bv[w * 32 + l31];
            int c = w * 32 + l31;
            int ks2 = c >> 4, kh = (c >> 3) & 1, j2 = c & 7;
            #pragma unroll
            for (int r = 0; r < 16; ++r) {
                int rowLocal = (r & 3) + 8 * (r >> 2) + 4 * half;
                VtF[ks2 * 512 + (rowLocal + 32 * kh) * 8 + j2] = f2bf(Cm[r] + bcol);
            }
        }
        __syncthreads();   // VtF written (cross-wave read next)
        // ---- V = Vt @ Wo -> Vf frags ----
        short8 a2[8];
        #pragma unroll
        for (int ks = 0; ks < 8; ++ks)
            a2[ks] = *(const short8*)&VtF[ks * 512 + lane * 8];
        {
            f32x16 Cm;
            #pragma unroll
            for (int r = 0; r < 16; ++r) Cm[r] = 0.f;
            CHAIN(a2, Cm, WfG + 49152);
            int c = w * 32 + l31;
            #pragma unroll
            for (int r = 0; r < 16; ++r) {
                int row = g0 + (r & 3) + 8 * (r >> 2) + 4 * half;
                if (row < ROWS_S) {
                    int tile = row / 25, vv = row - tile * 25;
                    size_t dst = ((((size_t)tile * 4 + (c >> 5)) * 2 + (vv >> 4)) * 64
                                  + ((c & 31) + 32 * ((vv & 15) >> 3))) * 8 + (vv & 7);
                    Vf[dst] = f2bf(Cm[r]);
                }
            }
        }
    }
    #undef CHAIN
}

// ============ kernel 2: MFMA fused attention + residual + LN ============
// CONFIG LOCKED — k_attn experiment ledger (7 variants, 56.5us floor):
//   bounds(256,2)+47K LDS      = 56.5us  <- this config (register attsum + spill)
//   bounds(256,4)              = 170us   (VGPR 64, catastrophic spill)
//   no bounds (VGPR 156)       = 67us    (2-wave occupancy bin)
//   bounds(256,2)+26K overlay  = 56.5us  (occupancy-neutral; kept: smaller LDS)
//   320thr/5-wave              = 90us    (uneven SIMD fill + 5-way reduce)
//   LDS-atomicAdd accumulator  = 433us   (r9: 64 ds-RMW/thread/iter serializes;
//                                        spill is throughput-cost, atomics are
//                                        serialization-cost — spill wins)
// ~14MB/dispatch spill traffic (WRITE 24 vs 10 att) is the known cost of
// attsum[64]+ctx[64] > 128 regs; every alternative measured worse.
__global__ __launch_bounds__(256, 2) void k_attn(
    const ushort* __restrict__ Qf, const ushort* __restrict__ Kf,
    const ushort* __restrict__ Vf, const ushort* __restrict__ catC,
    const float* __restrict__ bo, float* __restrict__ att) {
    __shared__ __align__(16) char smem[26016];
    float*  catb = (float*)smem;
    ushort* qls  = (ushort*)(smem + 12912);
    float (*red)[50][65] = (float (*)[50][65])smem;

    int pair = blockIdx.x;                    // n*8 + t
    int t = pair & 7;
    int tid = threadIdx.x;
    int wv = tid >> 6, lane = tid & 63;
    int q = lane & 31, half = lane >> 5;

    {
        const uint* cc = (const uint*)catC + (size_t)pair * 1600;
        for (int i2 = tid; i2 < 1600; i2 += 256) {
            uint u = cc[i2];
            int r = i2 >> 6, c2 = (i2 & 63) * 2;
            catb[r * 129 + c2]     = bf2f(u & 0xffffu) + bo[c2];
            catb[r * 129 + c2 + 1] = bf2f(u >> 16) + bo[c2 + 1];
        }
    }
    {
        const uint* qp = (const uint*)(Qf + (size_t)pair * 4096);
        uint* ql = (uint*)qls;
        for (int i2 = tid; i2 < 2048; i2 += 256) ql[i2] = qp[i2];
    }
    __syncthreads();

    int qc = q < 25 ? q : 24;
    float attsum[64];
    #pragma unroll
    for (int i = 0; i < 64; ++i) attsum[i] = 0.f;
    float Csc = 0.f;

    const float CEXP = (float)(1.4426950408889634 * 0.08838834764831845);

    const ushort* kbase = Kf + (size_t)t * 4096 + lane * 8;
    short8 kf[8];
    #pragma unroll
    for (int ks = 0; ks < 8; ++ks)
        kf[ks] = *(const short8*)(kbase + (size_t)wv * 32768 + ks * 512);

    int cnt = (wv == 0) ? 7 : 6;
    for (int mi = 0; mi < cnt; ++mi) {
        int m = wv + 4 * mi;

        f32x16 S;
        #pragma unroll
        for (int r = 0; r < 16; ++r) S[r] = 0.f;
        #pragma unroll
        for (int ks = 0; ks < 8; ++ks) {
            short8 qv = *(const short8*)(qls + ks * 512 + lane * 8);
            S = __builtin_amdgcn_mfma_f32_32x32x16_bf16(kf[ks], qv, S, 0, 0, 0);
        }

        float p[16], mx = -3e38f;
        #pragma unroll
        for (int r = 0; r < 16; ++r) {
            int key = (r & 3) + 8 * (r >> 2) + 4 * half;
            float v = (key < 25) ? S[r] : -3e38f;
            p[r] = v; mx = fmaxf(mx, v);
        }
        mx = fmaxf(mx, __shfl_xor(mx, 32));
        float sum = 0.f;
        #pragma unroll
        for (int r = 0; r < 16; ++r) { p[r] = exp2f((p[r] - mx) * CEXP); sum += p[r]; }
        sum += __shfl_xor(sum, 32);
        float inv = 1.f / sum;

        const ushort* vp = Vf + ((size_t)(m * 8 + t)) * 4096 + lane * 8;
        short8 vf0 = *(const short8*)(vp);
        short8 vf1 = *(const short8*)(vp + 512);
        short8 vf2 = *(const short8*)(vp + 1024);
        short8 vf3 = *(const short8*)(vp + 1536);
        short8 vf4 = *(const short8*)(vp + 2048);
        short8 vf5 = *(const short8*)(vp + 2560);
        short8 vf6 = *(const short8*)(vp + 3072);
        short8 vf7 = *(const short8*)(vp + 3584);
        #pragma unroll
        for (int ks = 0; ks < 8; ++ks)
            kf[ks] = *(const short8*)(kbase + (size_t)(m + 4) * 32768 + ks * 512);

        uint o01   = pkbf(p[0] * inv,  p[1] * inv);
        uint o23   = pkbf(p[2] * inv,  p[3] * inv);
        uint o45   = pkbf(p[4] * inv,  p[5] * inv);
        uint o67   = pkbf(p[6] * inv,  p[7] * inv);
        uint o89   = pkbf(p[8] * inv,  p[9] * inv);
        uint o1011 = pkbf(p[10] * inv, p[11] * inv);
        uint o1213 = pkbf(p[12] * inv, p[13] * inv);
        uint o1415 = pkbf(p[14] * inv, p[15] * inv);
        bool h0 = (half == 0);
        uint rA = __shfl_xor(h0 ? o45 : o01, 32);
        uint rB = __shfl_xor(h0 ? o67 : o23, 32);
        uint rC = __shfl_xor(h0 ? o1213 : o89, 32);
        uint rD = __shfl_xor(h0 ? o1415 : o1011, 32);
        pk_t P0, P1;
        P0.u4 = h0 ? make_uint4(o01, o23, rA, rB) : make_uint4(rA, rB, o45, o67);
        P1.u4 = h0 ? make_uint4(o89, o1011, rC, rD) : make_uint4(rC, rD, o1213, o1415);
        short8 pb0 = P0.s8, pb1 = P1.s8;

        f32x16 ctx[4];
        #pragma unroll
        for (int mt = 0; mt < 4; ++mt) {
            #pragma unroll
            for (int r = 0; r < 16; ++r) ctx[mt][r] = 0.f;
        }
        ctx[0] = __builtin_amdgcn_mfma_f32_32x32x16_bf16(vf0, pb0, ctx[0], 0, 0, 0);
        ctx[0] = __builtin_amdgcn_mfma_f32_32x32x16_bf16(vf1, pb1, ctx[0], 0, 0, 0);
        ctx[1] = __builtin_amdgcn_mfma_f32_32x32x16_bf16(vf2, pb0, ctx[1], 0, 0, 0);
        ctx[1] = __builtin_amdgcn_mfma_f32_32x32x16_bf16(vf3, pb1, ctx[1], 0, 0, 0);
        ctx[2] = __builtin_amdgcn_mfma_f32_32x32x16_bf16(vf4, pb0, ctx[2], 0, 0, 0);
        ctx[2] = __builtin_amdgcn_mfma_f32_32x32x16_bf16(vf5, pb1, ctx[2], 0, 0, 0);
        ctx[3] = __builtin_amdgcn_mfma_f32_32x32x16_bf16(vf6, pb0, ctx[3], 0, 0, 0);
        ctx[3] = __builtin_amdgcn_mfma_f32_32x32x16_bf16(vf7, pb1, ctx[3], 0, 0, 0);

        float s1 = 0.f, s2 = 0.f;
        #pragma unroll
        for (int mt = 0; mt < 4; ++mt) {
            float t1 = 0.f, t2 = 0.f;
            #pragma unroll
            for (int r = 0; r < 16; ++r) {
                int c = mt * 32 + (r & 3) + 8 * (r >> 2) + 4 * half;
                float xv = ctx[mt][r] + catb[qc * 129 + c];
                ctx[mt][r] = xv;
                t1 += xv; t2 = fmaf(xv, xv, t2);
            }
            s1 += t1; s2 += t2;
        }
        s1 += __shfl_xor(s1, 32); s2 += __shfl_xor(s2, 32);
        float mu = s1 * (1.f / 128.f);
        float var = s2 * (1.f / 128.f) - mu * mu;
        var = fmaxf(var, 0.f);
        float rs = rsqrtf(var + 1e-12f);
        #pragma unroll
        for (int i = 0; i < 64; ++i)
            attsum[i] = fmaf(ctx[i >> 4][i & 15], rs, attsum[i]);
        Csc = fmaf(-mu, rs, Csc);
    }

    __syncthreads();   // catb/qls dead past this point; red overlays them
    int s = half * 25 + q;
    bool act = q < 25;
    if ((wv == 1 || wv == 3) && act) {
        float (*rg)[65] = red[wv >> 1];
        #pragma unroll
        for (int i = 0; i < 64; ++i) rg[s][i] = attsum[i];
        rg[s][64] = Csc;
    }
    __syncthreads();
    if ((wv == 0 || wv == 2) && act) {
        float (*rg)[65] = red[wv >> 1];
        #pragma unroll
        for (int i = 0; i < 64; ++i) attsum[i] += rg[s][i];
        Csc += rg[s][64];
    }
    __syncthreads();
    if (wv == 2 && act) {
        #pragma unroll
        for (int i = 0; i < 64; ++i) red[0][s][i] = attsum[i];
        red[0][s][64] = Csc;
    }
    __syncthreads();
    if (wv == 0 && act) {
        #pragma unroll
        for (int i = 0; i < 64; ++i) attsum[i] += red[0][s][i];
        Csc += red[0][s][64];
        float* ap = att + (size_t)pair * TILE + q * 128;
        #pragma unroll
        for (int mt = 0; mt < 4; ++mt) {
            #pragma unroll
            for (int rg4 = 0; rg4 < 4; ++rg4) {
                int c0 = mt * 32 + 8 * rg4 + 4 * half;
                int i0 = mt * 16 + rg4 * 4;
                float4 o;
                o.x = attsum[i0 + 0] + Csc; o.y = attsum[i0 + 1] + Csc;
                o.z = attsum[i0 + 2] + Csc; o.w = attsum[i0 + 3] + Csc;
                *(float4*)&ap[c0] = o;
            }
        }
    }
}

// ============ kernel 2.5: materialize protos (mean of 5 support rows) ============
__global__ __launch_bounds__(256) void k_proto(
    const float* __restrict__ att, float* __restrict__ proto) {
    int b = blockIdx.x;             // 40 blocks: j = b>>3, chunk = b&7
    int j = b >> 3, chunk = b & 7;
    const float4* s0 = (const float4*)(att + (size_t)(NQ + j * 5 + 0) * ROW);
    const float4* s1 = (const float4*)(att + (size_t)(NQ + j * 5 + 1) * ROW);
    const float4* s2 = (const float4*)(att + (size_t)(NQ + j * 5 + 2) * ROW);
    const float4* s3 = (const float4*)(att + (size_t)(NQ + j * 5 + 3) * ROW);
    const float4* s4 = (const float4*)(att + (size_t)(NQ + j * 5 + 4) * ROW);
    float4* pr = (float4*)(proto + (size_t)j * ROW);
    int e0 = chunk * 800, e1 = e0 + 800;
    for (int e4 = e0 + threadIdx.x; e4 < e1; e4 += 256) {
        float4 q0 = s0[e4], q1 = s1[e4], q2 = s2[e4], q3 = s3[e4], q4 = s4[e4];
        float4 o;
        o.x = 0.2f * (q0.x + q1.x + q2.x + q3.x + q4.x);
        o.y = 0.2f * (q0.y + q1.y + q2.y + q3.y + q4.y);
        o.z = 0.2f * (q0.z + q1.z + q2.z + q3.z + q4.z);
        o.w = 0.2f * (q0.w + q1.w + q2.w + q3.w + q4.w);
        pr[e4] = o;
    }
}

// ============ kernel 3: fused distances + log-softmax loss/acc ============
__global__ __launch_bounds__(256) void k_dist_loss(
    const float* __restrict__ att, const float* __restrict__ proto,
    const float* __restrict__ ln_g,
    float* __restrict__ dist, int* __restrict__ counter,
    float* __restrict__ out) {
    int i = blockIdx.x;   // query index 0..74
    const float4* a  = (const float4*)(att + (size_t)i * ROW);
    const float4* p0 = (const float4*)(proto + (size_t)0 * ROW);
    const float4* p1 = (const float4*)(proto + (size_t)1 * ROW);
    const float4* p2 = (const float4*)(proto + (size_t)2 * ROW);
    const float4* p3 = (const float4*)(proto + (size_t)3 * ROW);
    const float4* p4 = (const float4*)(proto + (size_t)4 * ROW);
    float d0 = 0.f, d1 = 0.f, d2 = 0.f, d3 = 0.f, d4 = 0.f;
    for (int e4 = threadIdx.x; e4 < 6400; e4 += 256) {
        float4 av = a[e4];
        float4 g4 = *(const float4*)(ln_g + (e4 & 31) * 4);
        float gx = g4.x * g4.x, gy = g4.y * g4.y, gz = g4.z * g4.z, gw = g4.w * g4.w;
        #define ACC(PD, DD) do {                                              \
            float4 pv = PD[e4];                                               \
            float dx = av.x - pv.x, dy = av.y - pv.y;                         \
            float dz = av.z - pv.z, dw = av.w - pv.w;                         \
            DD = fmaf(gx, dx * dx, DD);                                       \
            DD = fmaf(gy, dy * dy, DD);                                       \
            DD = fmaf(gz, dz * dz, DD);                                       \
            DD = fmaf(gw, dw * dw, DD);                                       \
        } while (0)
        ACC(p0, d0); ACC(p1, d1); ACC(p2, d2); ACC(p3, d3); ACC(p4, d4);
        #undef ACC
    }
    #pragma unroll
    for (int msk = 32; msk >= 1; msk >>= 1) {
        d0 += __shfl_xor(d0, msk);
        d1 += __shfl_xor(d1, msk);
        d2 += __shfl_xor(d2, msk);
        d3 += __shfl_xor(d3, msk);
        d4 += __shfl_xor(d4, msk);
    }
    __shared__ float part[4][5];
    __shared__ int lastFlag;
    int lane = threadIdx.x & 63, wv = threadIdx.x >> 6;
    if (lane == 0) {
        part[wv][0] = d0; part[wv][1] = d1; part[wv][2] = d2;
        part[wv][3] = d3; part[wv][4] = d4;
    }
    __syncthreads();
    if (threadIdx.x == 0) {
        #pragma unroll
        for (int j = 0; j < 5; ++j) {
            float total = (part[0][j] + part[1][j] + part[2][j] + part[3][j]) * (1.f / 625.f);
            __hip_atomic_store(&dist[i * 5 + j], total, __ATOMIC_RELEASE, __HIP_MEMORY_SCOPE_AGENT);
        }
        int tk = __hip_atomic_fetch_add(counter, 1, __ATOMIC_ACQ_REL, __HIP_MEMORY_SCOPE_AGENT);
        lastFlag = (tk == 74);
    }
    __syncthreads();
    if (!lastFlag) return;

    int iq = threadIdx.x;
    float li = 0.f, ok = 0.f;
    if (iq < NQ) {
        float dd[5];
        #pragma unroll
        for (int jj = 0; jj < 5; ++jj)
            dd[jj] = __hip_atomic_load(&dist[iq * 5 + jj], __ATOMIC_ACQUIRE, __HIP_MEMORY_SCOPE_AGENT);
        int cls = iq / NQRY;
        float mind = dd[0];
        int best = 0;
        #pragma unroll
        for (int jj = 1; jj < 5; ++jj) {
            if (dd[jj] < mind) mind = dd[jj];
            if (dd[jj] < dd[best]) best = jj;
        }
        float sume = 0.f;
        #pragma unroll
        for (int jj = 0; jj < 5; ++jj) sume += expf(mind - dd[jj]);
        float lse = logf(sume) - mind;
        li = dd[cls] + lse;
        ok = (best == cls) ? 1.f : 0.f;
    }
    #pragma unroll
    for (int msk = 32; msk >= 1; msk >>= 1) {
        li += __shfl_xor(li, msk);
        ok += __shfl_xor(ok, msk);
    }
    if (lane == 0) { part[wv][0] = li; part[wv][1] = ok; }
    __syncthreads();
    if (threadIdx.x == 0) {
        out[0] = (part[0][0] + part[1][0] + part[2][0] + part[3][0]) / 75.f;
        out[1] = (part[0][1] + part[1][1] + part[2][1] + part[3][1]) / 75.f;
    }
}

extern "C" void kernel_launch(void* const* d_in, const int* in_sizes, int n_in,
                              void* d_out, int out_size, void* d_ws, size_t ws_size,
                              hipStream_t stream) {
    const float* input = (const float*)d_in[0];
    const float* Wq   = (const float*)d_in[1];
    const float* bq   = (const float*)d_in[2];
    const float* Wk   = (const float*)d_in[3];
    const float* bk   = (const float*)d_in[4];
    const float* Wv   = (const float*)d_in[5];
    const float* bv   = (const float*)d_in[6];
    const float* Wo   = (const float*)d_in[7];
    const float* bo   = (const float*)d_in[8];
    const float* ln_g = (const float*)d_in[9];
    const float* ln_b = (const float*)d_in[10];  // cancels in the distance
    const int* target = (const int*)d_in[11];
    float* out = (float*)d_out;
    (void)ln_b;

    float* ws = (float*)d_ws;
    ushort* catC = (ushort*)ws;                              // 2,560,000 u16
    ushort* Qf   = catC + 2560000;                           // 3,276,800
    ushort* Kf   = Qf + 3276800;                             //   819,200
    ushort* Vf   = Kf + 819200;                              //   819,200 (K prefetch overrun pad)
    float*  att  = (float*)(Vf + 819200);                    // 100*25600 fp32
    float*  distb = att + 2560000;                           // 375 (+pad)
    int*    counter = (int*)(distb + 512);
    ushort* WfG  = (ushort*)(counter + 16);                  // 4 x 16384 u16 = 128 KB
    int*    ordG = (int*)(WfG + 65536);                      // 100 ints
    // proto aliases catC: catC's last reader is k_attn; k_proto runs after.
    float*  proto = (float*)catC;                            // 5*25600 fp32 = 512 KB
    // total ~25.3 MB

    k_pack<<<5, 256, 0, stream>>>(Wq, Wk, Wv, Wo, target, WfG, ordG);
    k_proj<<<RB_Q + RB_S, 256, 0, stream>>>(input, ordG, WfG, bq, bk, bv,
                                            catC, Qf, Kf, Vf, counter);
    k_attn<<<800, 256, 0, stream>>>(Qf, Kf, Vf, catC, bo, att);
    k_proto<<<40, 256, 0, stream>>>(att, proto);
    k_dist_loss<<<75, 256, 0, stream>>>(att, proto, ln_g, distb, counter, out);
}